// Round 5
// baseline (405.339 us; speedup 1.0000x reference)
//
#include <hip/hip_runtime.h>
#include <cstdint>
#include <cstddef>

#define B_   16
#define C_   512
#define H_   32
#define W_   32
#define HW_  1024
#define TC_  64
#define T_   48

typedef unsigned short u16;
typedef __attribute__((ext_vector_type(8))) short short8v;
typedef __attribute__((ext_vector_type(4))) float f32x4;

// ---------------------------------------------------------------------------
// bf16 helpers
// ---------------------------------------------------------------------------
__device__ __forceinline__ u16 tobf(float x) {
    unsigned u = __float_as_uint(x);
    return (u16)((u + 0x7FFFu + ((u >> 16) & 1u)) >> 16);    // RTNE
}
__device__ __forceinline__ unsigned pack_hilo(float x) {
    unsigned u = __float_as_uint(x);
    unsigned hi = (u + 0x7FFFu + ((u >> 16) & 1u)) >> 16;
    float hif = __uint_as_float(hi << 16);
    float lof = x - hif;
    unsigned ul = __float_as_uint(lof);
    unsigned lo = (ul + 0x7FFFu + ((ul >> 16) & 1u)) >> 16;
    return (hi << 16) | lo;
}
__device__ __forceinline__ float compose_hilo(u16 hi, u16 lo) {
    return __uint_as_float(((unsigned)hi) << 16) + __uint_as_float(((unsigned)lo) << 16);
}
__device__ __forceinline__ float frombf(u16 h) {
    return __uint_as_float(((unsigned)h) << 16);
}

__device__ __forceinline__ void gld16(const void* g, void* l) {
    __builtin_amdgcn_global_load_lds(
        (const __attribute__((address_space(1))) void*)g,
        (__attribute__((address_space(3))) void*)l, 16, 0, 0);
}

// ---------------------------------------------------------------------------
// 1) Frobenius-norm helpers
// ---------------------------------------------------------------------------
__global__ void k_colsq(const float* __restrict__ x, float* __restrict__ partial) {
    int bid = blockIdx.x;
    int col = (bid & 3) * 256 + threadIdx.x;
    int r0  = (bid >> 2) * 256;
    const float* p = x + (size_t)r0 * HW_ + col;
    float s = 0.f;
    for (int r = 0; r < 256; ++r) { float v = p[(size_t)r * HW_]; s += v * v; }
    partial[(size_t)(bid >> 2) * HW_ + col] = s;
}

__global__ void k_rsqrt(const float* __restrict__ partial, float* __restrict__ ninv) {
    int i = blockIdx.x * 256 + threadIdx.x;
    if (i < HW_) {
        float s = 0.f;
        for (int r = 0; r < 32; ++r) s += partial[(size_t)r * HW_ + i];
        ninv[i] = rsqrtf(s);
    }
}

// ---------------------------------------------------------------------------
// 2) transpose + normalize + split: x [B,C,HW] -> xn planes [B,HW,C] bf16 hi/lo
// ---------------------------------------------------------------------------
__global__ void k_transpose(const float* __restrict__ x, const float* __restrict__ ninv,
                            u16* __restrict__ obH, u16* __restrict__ obL) {
    __shared__ float tile[32][33];
    int b  = blockIdx.z;
    int m0 = blockIdx.x * 32, c0 = blockIdx.y * 32;
    int tx = threadIdx.x, ty = threadIdx.y;
    const float* xb = x + (size_t)b * C_ * HW_;
    #pragma unroll
    for (int j = 0; j < 32; j += 8)
        tile[ty + j][tx] = xb[(size_t)(c0 + ty + j) * HW_ + m0 + tx];
    __syncthreads();
    size_t base = (size_t)b * HW_ * C_;
    #pragma unroll
    for (int j = 0; j < 32; j += 8) {
        int m = m0 + ty + j;
        unsigned pk = pack_hilo(tile[tx][ty + j] * ninv[m]);
        size_t idx = base + (size_t)m * C_ + c0 + tx;
        obH[idx] = (u16)(pk >> 16);
        obL[idx] = (u16)pk;
    }
}

// ---------------------------------------------------------------------------
// 3) weight prep
// ---------------------------------------------------------------------------
__global__ void k_packW(const float* __restrict__ in, u16* __restrict__ oh,
                        u16* __restrict__ ol) {
    size_t i = (size_t)blockIdx.x * 256 + threadIdx.x;
    unsigned pk = pack_hilo(in[i]);
    oh[i] = (u16)(pk >> 16); ol[i] = (u16)pk;
}
__global__ void k_packFG(const float* __restrict__ fW, const float* __restrict__ gW,
                         const float* __restrict__ fb, const float* __restrict__ gb,
                         u16* __restrict__ oh, u16* __restrict__ ol,
                         float* __restrict__ fgb) {
    int idx = blockIdx.x * 256 + threadIdx.x;   // 65536
    int row = idx >> 9, c = idx & 511;
    float v = (row < 64) ? fW[row * 512 + c] : gW[(row - 64) * 512 + c];
    unsigned pk = pack_hilo(v);
    oh[idx] = (u16)(pk >> 16); ol[idx] = (u16)pk;
    if (idx < 128) fgb[idx] = (idx < 64) ? fb[idx] : gb[idx - 64];
}

// ---------------------------------------------------------------------------
// 4) unified planar bf16 MFMA GEMM: C = A[M,K] * B[N,K]^T
//    128x128 tile, BK=32, 4 waves, DOUBLE-BUFFERED 2-phase pipeline:
//    {STAGE(kt+1 -> other half) ; ds_read+MFMA(this half) ; barrier}.
//    LDS swizzle (verified r3/r4): chunk li: rp=li*8+(lane>>3),
//    gg=(lane&7)^(rp&7), r=rp*2+(gg>>2), kc=k0+(gg&3)*8; fragment: rp=r>>1,
//    gg=((r&1)<<2)+g, off=rp*64+((gg^(rp&7))<<3).
//    EPI 0: Cf fp32 = acc
//    EPI 1: planar hi/lo = acc + bias[row]
//    EPI 2: Ch = bf16(scale*acc + compose(Ch,Cl))   (in-place fdd)
//    EPI 3: planar hi/lo = acc + bias[col]
//    EPI 4: Ch = bf16(acc)
//    EPI 5: Ch = bf16(acc + bias[row])
// ---------------------------------------------------------------------------
template<int PERMB, int SPLITA, int SPLITB, int EPI>
__global__ __launch_bounds__(256) void k_gemm(
    const u16* __restrict__ Ah, const u16* __restrict__ Al,
    const u16* __restrict__ Bh, const u16* __restrict__ Bl,
    const float* __restrict__ bias,
    float* __restrict__ Cf, u16* __restrict__ Ch, u16* __restrict__ Cl,
    const float* __restrict__ scaleP,
    int N, int K, int lda, int ldb, long sA, long sB, long sC)
{
    constexpr int PLANES = 2 + SPLITA + SPLITB;
    constexpr int CPW = 2 * PLANES;             // staging chunks per wave
    constexpr int HALF = PLANES * 4096;
    __shared__ u16 lds[2 * HALF];

    const int b = blockIdx.z;
    const u16* pAh = Ah + (size_t)b * sA;
    const u16* pAl = SPLITA ? Al + (size_t)b * sA : nullptr;
    const u16* pBh = Bh + (size_t)b * sB;
    const u16* pBl = SPLITB ? Bl + (size_t)b * sB : nullptr;
    const int m0 = blockIdx.y * 128, n0 = blockIdx.x * 128;
    const int tid = threadIdx.x, wave = tid >> 6, lane = tid & 63;
    const int wm = wave >> 1, wn = wave & 1;
    const int g = lane >> 4;

    f32x4 acc[4][4];
    #pragma unroll
    for (int i = 0; i < 4; ++i)
        #pragma unroll
        for (int j = 0; j < 4; ++j) { f32x4 z = {0.f,0.f,0.f,0.f}; acc[i][j] = z; }

    auto STAGE = [&](int kt, int hbase) {
        const int k0 = kt << 5;
        #pragma unroll
        for (int q = 0; q < CPW; ++q) {
            int ci = wave * CPW + q;
            int pl = ci >> 3, li = ci & 7;
            bool isA = pl < (1 + SPLITA);
            const u16* gp;
            int lbase;
            if (pl == 0)                      { gp = pAh; lbase = 0; }
            else if (SPLITA && pl == 1)       { gp = pAl; lbase = 4096; }
            else if (pl == 1 + SPLITA)        { gp = pBh; lbase = (1 + SPLITA) * 4096; }
            else                              { gp = pBl; lbase = (2 + SPLITA) * 4096; }
            int ld = isA ? lda : ldb;
            int rb = isA ? m0 : n0;
            int rp = li * 8 + (lane >> 3);
            int gg = (lane & 7) ^ (rp & 7);
            int r  = rp * 2 + (gg >> 2);
            int kc = k0 + (gg & 3) * 8;
            int rowg = rb + r;
            if (PERMB && !isA) rowg = ((rowg & 31) << 5) | (rowg >> 5);
            gld16(gp + (size_t)rowg * ld + kc, lds + hbase + lbase + li * 512 + lane * 8);
        }
    };

    auto COMPUTE = [&](int hbase) {
        const u16* AsH = lds + hbase;
        const u16* AsL = lds + hbase + 4096;
        const u16* BsH = lds + hbase + (1 + SPLITA) * 4096;
        const u16* BsL = lds + hbase + (2 + SPLITA) * 4096;

        short8v ah[4], alv[4];
        #pragma unroll
        for (int i = 0; i < 4; ++i) {
            int r = wm * 64 + i * 16 + (lane & 15);
            int rp = r >> 1, gg = ((r & 1) << 2) + g;
            int off = rp * 64 + ((gg ^ (rp & 7)) << 3);
            ah[i] = *(const short8v*)(AsH + off);
            if (SPLITA) alv[i] = *(const short8v*)(AsL + off);
        }
        #pragma unroll
        for (int j = 0; j < 4; ++j) {
            int r = wn * 64 + j * 16 + (lane & 15);
            int rp = r >> 1, gg = ((r & 1) << 2) + g;
            int off = rp * 64 + ((gg ^ (rp & 7)) << 3);
            short8v bh = *(const short8v*)(BsH + off);
            short8v bl;
            if (SPLITB) bl = *(const short8v*)(BsL + off);
            #pragma unroll
            for (int i = 0; i < 4; ++i) {
                acc[i][j] = __builtin_amdgcn_mfma_f32_16x16x32_bf16(ah[i], bh, acc[i][j], 0, 0, 0);
                if (SPLITB)
                    acc[i][j] = __builtin_amdgcn_mfma_f32_16x16x32_bf16(ah[i], bl, acc[i][j], 0, 0, 0);
                if (SPLITA)
                    acc[i][j] = __builtin_amdgcn_mfma_f32_16x16x32_bf16(alv[i], bh, acc[i][j], 0, 0, 0);
            }
        }
    };

    const int nkt = K >> 5;     // always even here (2, 16, 32)
    STAGE(0, 0);
    __syncthreads();
    for (int kt = 0; kt < nkt; kt += 2) {
        STAGE(kt + 1, HALF);
        COMPUTE(0);
        __syncthreads();
        if (kt + 2 < nkt) STAGE(kt + 2, 0);
        COMPUTE(HALF);
        if (kt + 2 < nkt) __syncthreads();
    }

    const float sc = (EPI == 2) ? scaleP[0] : 0.f;
    const int colbase = n0 + wn * 64 + (lane & 15);
    const int rowbase = m0 + wm * 64 + ((lane >> 4) << 2);
    #pragma unroll
    for (int i = 0; i < 4; ++i)
        #pragma unroll
        for (int j = 0; j < 4; ++j) {
            int col = colbase + j * 16;
            #pragma unroll
            for (int rg = 0; rg < 4; ++rg) {
                int row = rowbase + i * 16 + rg;
                size_t idx = (size_t)b * sC + (size_t)row * N + col;
                float a = acc[i][j][rg];
                if (EPI == 0) {
                    Cf[idx] = a;
                } else if (EPI == 1 || EPI == 3) {
                    float v = a + ((EPI == 1) ? bias[row] : bias[col]);
                    unsigned pk = pack_hilo(v);
                    Ch[idx] = (u16)(pk >> 16); Cl[idx] = (u16)pk;
                } else if (EPI == 2) {
                    float v = sc * a + compose_hilo(Ch[idx], Cl[idx]);
                    Ch[idx] = tobf(v);
                } else if (EPI == 4) {
                    Ch[idx] = tobf(a);
                } else {   // EPI == 5
                    Ch[idx] = tobf(a + bias[row]);
                }
            }
        }
}

// ---------------------------------------------------------------------------
// 5) row softmax on bf16 S, u16 in-place
// ---------------------------------------------------------------------------
__global__ __launch_bounds__(256) void k_softmax(u16* __restrict__ S) {
    size_t row = blockIdx.x;
    u16* r = S + row * (size_t)HW_;
    int t = threadIdx.x;
    ushort4 raw = ((const ushort4*)r)[t];
    float v0 = frombf(raw.x), v1 = frombf(raw.y), v2 = frombf(raw.z), v3 = frombf(raw.w);

    __shared__ float redm[4], reds[4];
    int wid = t >> 6, lane = t & 63;

    float m = fmaxf(fmaxf(v0, v1), fmaxf(v2, v3));
    for (int o = 32; o > 0; o >>= 1) m = fmaxf(m, __shfl_down(m, o));
    if (lane == 0) redm[wid] = m;
    __syncthreads();
    if (t == 0) redm[0] = fmaxf(fmaxf(redm[0], redm[1]), fmaxf(redm[2], redm[3]));
    __syncthreads();
    m = redm[0];

    v0 = expf(v0 - m); v1 = expf(v1 - m); v2 = expf(v2 - m); v3 = expf(v3 - m);
    float s = v0 + v1 + v2 + v3;
    for (int o = 32; o > 0; o >>= 1) s += __shfl_down(s, o);
    if (lane == 0) reds[wid] = s;
    __syncthreads();
    if (t == 0) reds[0] = reds[0] + reds[1] + reds[2] + reds[3];
    __syncthreads();
    float inv = 1.f / reds[0];
    ushort4 o4;
    o4.x = tobf(v0 * inv); o4.y = tobf(v1 * inv);
    o4.z = tobf(v2 * inv); o4.w = tobf(v3 * inv);
    ((ushort4*)r)[t] = o4;
}

// ---------------------------------------------------------------------------
// 6) single-plane u16 transpose of fdd flat view [512][1024] -> fddT [1024][512]
// ---------------------------------------------------------------------------
__global__ void k_tposeU1(const u16* __restrict__ src, u16* __restrict__ dst) {
    __shared__ u16 tile[32][33];
    int b = blockIdx.z;
    const u16* sb = src + (size_t)b * (C_ * HW_);
    u16* db = dst + (size_t)b * (C_ * HW_);
    int c0 = blockIdx.x * 32, r0 = blockIdx.y * 32;     // src [512 r][1024 c]
    int tx = threadIdx.x, ty = threadIdx.y;
    #pragma unroll
    for (int j = 0; j < 32; j += 8)
        tile[ty + j][tx] = sb[(size_t)(r0 + ty + j) * HW_ + c0 + tx];
    __syncthreads();
    #pragma unroll
    for (int j = 0; j < 32; j += 8)
        db[(size_t)(c0 + ty + j) * C_ + r0 + tx] = tile[tx][ty + j];
}

// ---------------------------------------------------------------------------
// 7) top-48: tau-prune + compact + sort (verified r3/r4)
// ---------------------------------------------------------------------------
__device__ __forceinline__ float sort64_desc(float v, int lane) {
    #pragma unroll
    for (int k = 2; k <= 64; k <<= 1) {
        #pragma unroll
        for (int j = k >> 1; j > 0; j >>= 1) {
            float o = __shfl_xor(v, j);
            bool takeMax = (((lane & k) == 0) == ((lane & j) == 0));
            v = takeMax ? fmaxf(v, o) : fminf(v, o);
        }
    }
    return v;
}
__device__ __forceinline__ float bmerge64_desc(float a, float b, int lane) {
    float br = __shfl(b, 63 - lane);
    float c = fmaxf(a, br);
    #pragma unroll
    for (int j = 32; j > 0; j >>= 1) {
        float o = __shfl_xor(c, j);
        c = ((lane & j) == 0) ? fmaxf(c, o) : fminf(c, o);
    }
    return c;
}

__global__ __launch_bounds__(256) void k_topk(const float* __restrict__ corr,
                                              float* __restrict__ topv) {
    int row = blockIdx.x, tid = threadIdx.x, wave = tid >> 6, lane = tid & 63;
    const float4 e = ((const float4*)(corr + (size_t)row * HW_))[tid];
    float gm = fmaxf(fmaxf(e.x, e.y), fmaxf(e.z, e.w));
    float v = sort64_desc(gm, lane);

    __shared__ float ls[4][64];
    __shared__ float tau_s;
    __shared__ int cnt_s;
    __shared__ float buf[1024];
    ls[wave][lane] = v;
    buf[tid] = -INFINITY; buf[tid + 256] = -INFINITY;
    buf[tid + 512] = -INFINITY; buf[tid + 768] = -INFINITY;
    if (tid == 0) cnt_s = 0;
    __syncthreads();

    if (wave == 0) {
        float ab = bmerge64_desc(ls[0][lane], ls[1][lane], lane);
        float cd = bmerge64_desc(ls[2][lane], ls[3][lane], lane);
        float t  = bmerge64_desc(ab, cd, lane);
        if (lane == T_ - 1) tau_s = t;
    }
    __syncthreads();
    float tau = tau_s;

    int c = (e.x >= tau) + (e.y >= tau) + (e.z >= tau) + (e.w >= tau);
    int off = 0;
    if (c) off = atomicAdd(&cnt_s, c);
    if (e.x >= tau) buf[off++] = e.x;
    if (e.y >= tau) buf[off++] = e.y;
    if (e.z >= tau) buf[off++] = e.z;
    if (e.w >= tau) buf[off++] = e.w;
    __syncthreads();
    int cnt = cnt_s;

    if (cnt <= 128) {
        if (wave == 0) {
            float a  = sort64_desc(buf[lane], lane);
            float b2 = sort64_desc(buf[64 + lane], lane);
            float br = __shfl(b2, 63 - lane);
            float hi = fmaxf(a, br);
            #pragma unroll
            for (int j = 32; j > 0; j >>= 1) {
                float o = __shfl_xor(hi, j);
                hi = ((lane & j) == 0) ? fmaxf(hi, o) : fminf(hi, o);
            }
            if (lane < T_) topv[(size_t)row * T_ + lane] = fmaxf(hi, 0.f);
        }
    } else {
        int P = 256; while (P < cnt) P <<= 1;
        for (int k = 2; k <= P; k <<= 1)
            for (int j = k >> 1; j > 0; j >>= 1) {
                for (int t2 = tid; t2 < P; t2 += 256) {
                    int ixj = t2 ^ j;
                    if (ixj > t2) {
                        float a = buf[t2], b3 = buf[ixj];
                        bool desc = ((t2 & k) == 0);
                        if (desc ? (a < b3) : (a > b3)) { buf[t2] = b3; buf[ixj] = a; }
                    }
                }
                __syncthreads();
            }
        if (tid < T_) topv[(size_t)row * T_ + tid] = fmaxf(buf[tid], 0.f);
    }
}

// ---------------------------------------------------------------------------
// 8) column norm over (B,H) and final transpose
// ---------------------------------------------------------------------------
__global__ void k_colss(const float* __restrict__ topv, float* __restrict__ colss) {
    int o = blockIdx.x;
    int w = o / T_, t = o % T_;
    int lane = threadIdx.x;
    float s = 0.f;
    for (int i = lane; i < 512; i += 64) {
        int b = i >> 5, h = i & 31;
        float v = topv[(size_t)((b << 10) + (h << 5) + w) * T_ + t];
        s += v * v;
    }
    for (int off = 32; off > 0; off >>= 1) s += __shfl_down(s, off);
    if (lane == 0) colss[o] = s;
}

__global__ void k_final(const float* __restrict__ topv, const float* __restrict__ colss,
                        float* __restrict__ out) {
    int idx = blockIdx.x * 256 + threadIdx.x;
    if (idx >= B_ * T_ * HW_) return;
    int w = idx & 31;
    int h = (idx >> 5) & 31;
    int t = (idx >> 10) % T_;
    int b = idx / (T_ * HW_);
    float v = topv[(size_t)((b << 10) + (h << 5) + w) * T_ + t];
    out[idx] = v * rsqrtf(colss[w * T_ + t]);
}

// ---------------------------------------------------------------------------
extern "C" void kernel_launch(void* const* d_in, const int* in_sizes, int n_in,
                              void* d_out, int out_size, void* d_ws, size_t ws_size,
                              hipStream_t stream) {
    const float* x     = (const float*)d_in[0];
    const float* fW    = (const float*)d_in[1];
    const float* fb    = (const float*)d_in[2];
    const float* gW    = (const float*)d_in[3];
    const float* gb    = (const float*)d_in[4];
    const float* hW    = (const float*)d_in[5];
    const float* hb    = (const float*)d_in[6];
    const float* scale = (const float*)d_in[7];
    float* out = (float*)d_out;

    // byte-offset workspace layout (~144 MB, proven available)
    char* wsb = (char*)d_ws;
    float* part = (float*)(wsb + 0);                 // 131072 B
    float* ninv = (float*)(wsb + 131072);            // 4096 B
    u16*   hWh  = (u16*)(wsb + 135168);              // 524288 B
    u16*   hWl  = (u16*)(wsb + 659456);              // 524288 B (unused now)
    u16*   fgWh = (u16*)(wsb + 1183744);             // 131072 B
    u16*   fgWl = (u16*)(wsb + 1314816);             // 131072 B
    float* fgb  = (float*)(wsb + 1445888);           // 512 B
    u16*   xnH  = (u16*)(wsb + 1446400);             // 16777216 B (xn hi -> fdd bf16)
    u16*   xnL  = (u16*)(wsb + 18223616);            // 16777216 B (xn lo)
    u16*   fgH  = (u16*)(wsb + 35000832);            // 4194304 B (later topv)
    u16*   fgL  = (u16*)(wsb + 39195136);            // 4194304 B (later colss)
    u16*   hvTH = (u16*)(wsb + 43389440);            // 16777216 B (hv bf16 -> fddT)
    u16*   hvTL = (u16*)(wsb + 60166656);            // 16777216 B (unused now)
    float* S    = (float*)(wsb + 76943872);          // 67108864 B (S/P u16 -> corr fp32)
    float* topv = (float*)fgH;
    float* colss= (float*)fgL;
    u16*   Sp   = (u16*)S;                           // u16 S/P view [B*1024][1024]

    const long sXn = 524288;    // [1024][512] elements per batch
    const long sFG = 131072;    // [1024][128]
    const long sS  = 1048576;   // [1024][1024]

    // 1) per-pixel Frobenius norm
    k_colsq<<<128, 256, 0, stream>>>(x, part);
    k_rsqrt<<<4, 256, 0, stream>>>(part, ninv);

    // 2) normalized channel-last bf16-split planes
    k_transpose<<<dim3(32, 16, 16), dim3(32, 8), 0, stream>>>(x, ninv, xnH, xnL);

    // 3) weight planes
    k_packW<<<1024, 256, 0, stream>>>(hW, hWh, hWl);
    k_packFG<<<256, 256, 0, stream>>>(fW, gW, fb, gb, fgWh, fgWl, fgb);

    // 4) fg = xn @ [fW|gW]^T + bias[col]  (3-term, planar out [B,1024,128])
    k_gemm<0, 1, 1, 3><<<dim3(1, 8, 16), 256, 0, stream>>>(
        xnH, xnL, fgWh, fgWl, fgb, nullptr, fgH, fgL, nullptr,
        128, 512, 512, 512, sXn, 0, sFG);

    // 5) hv = hW @ xn^T + hb[row], 2-term (hW hi only), single bf16 plane out
    k_gemm<0, 0, 1, 5><<<dim3(8, 4, 16), 256, 0, stream>>>(
        hWh, nullptr, xnH, xnL, hb, nullptr, hvTH, nullptr, nullptr,
        1024, 512, 512, 512, 0, sXn, sXn);

    // 6) S = f @ perm(g)^T  (3-term, K=64, W-major keys) -> bf16 u16
    k_gemm<1, 1, 1, 4><<<dim3(8, 8, 16), 256, 0, stream>>>(
        fgH, fgL, fgH + 64, fgL + 64, nullptr, nullptr, Sp, nullptr, nullptr,
        1024, 64, 128, 128, sFG, sFG, sS);

    // 7) softmax rows, u16 in place -> P bf16
    k_softmax<<<B_ * HW_, 256, 0, stream>>>(Sp);

    // 8) fdd = bf16(scale*(P @ hv^T) + xn), 1-term, in place over xnH
    k_gemm<0, 0, 0, 2><<<dim3(4, 8, 16), 256, 0, stream>>>(
        Sp, nullptr, hvTH, nullptr, nullptr, nullptr, xnH, xnL, scale,
        512, 1024, 1024, 1024, sS, sXn, sXn);

    // 9) fddT: transpose flat [512][1024] view of fddH -> hvTH [1024][512]
    k_tposeU1<<<dim3(32, 16, 16), dim3(32, 8), 0, stream>>>(xnH, hvTH);

    // 10) corr = fdd @ fddT^T (1-term bf16) -> fp32 into S
    k_gemm<0, 0, 0, 0><<<dim3(8, 8, 16), 256, 0, stream>>>(
        xnH, nullptr, hvTH, nullptr, nullptr, S, nullptr, nullptr, nullptr,
        1024, 512, 512, 512, sXn, sXn, sS);

    // 11) top-48 desc + relu
    k_topk<<<B_ * HW_, 256, 0, stream>>>(S, topv);

    // 12) norm over (B,H) + output transpose
    k_colss<<<W_ * T_, 64, 0, stream>>>(topv, colss);
    k_final<<<(B_ * T_ * HW_ + 255) / 256, 256, 0, stream>>>(topv, colss, out);
}

// Round 6
// 262.529 us; speedup vs baseline: 1.5440x; 1.5440x over previous
//
#include <hip/hip_runtime.h>
#include <cstdint>
#include <cstddef>

#define B_   16
#define C_   512
#define H_   32
#define W_   32
#define HW_  1024
#define TC_  64
#define T_   48

typedef unsigned short u16;
typedef __attribute__((ext_vector_type(8))) short short8v;
typedef __attribute__((ext_vector_type(4))) float f32x4;

// ---------------------------------------------------------------------------
// bf16 helpers
// ---------------------------------------------------------------------------
__device__ __forceinline__ u16 tobf(float x) {
    unsigned u = __float_as_uint(x);
    return (u16)((u + 0x7FFFu + ((u >> 16) & 1u)) >> 16);    // RTNE
}
__device__ __forceinline__ unsigned pack_hilo(float x) {
    unsigned u = __float_as_uint(x);
    unsigned hi = (u + 0x7FFFu + ((u >> 16) & 1u)) >> 16;
    float hif = __uint_as_float(hi << 16);
    float lof = x - hif;
    unsigned ul = __float_as_uint(lof);
    unsigned lo = (ul + 0x7FFFu + ((ul >> 16) & 1u)) >> 16;
    return (hi << 16) | lo;
}
__device__ __forceinline__ float compose_hilo(u16 hi, u16 lo) {
    return __uint_as_float(((unsigned)hi) << 16) + __uint_as_float(((unsigned)lo) << 16);
}
__device__ __forceinline__ float frombf(u16 h) {
    return __uint_as_float(((unsigned)h) << 16);
}

__device__ __forceinline__ void gld16(const void* g, void* l) {
    __builtin_amdgcn_global_load_lds(
        (const __attribute__((address_space(1))) void*)g,
        (__attribute__((address_space(3))) void*)l, 16, 0, 0);
}

// ---------------------------------------------------------------------------
// 1) Frobenius-norm helpers
// ---------------------------------------------------------------------------
__global__ void k_colsq(const float* __restrict__ x, float* __restrict__ partial) {
    int bid = blockIdx.x;
    int col = (bid & 3) * 256 + threadIdx.x;
    int r0  = (bid >> 2) * 256;
    const float* p = x + (size_t)r0 * HW_ + col;
    float s = 0.f;
    for (int r = 0; r < 256; ++r) { float v = p[(size_t)r * HW_]; s += v * v; }
    partial[(size_t)(bid >> 2) * HW_ + col] = s;
}

__global__ void k_rsqrt(const float* __restrict__ partial, float* __restrict__ ninv) {
    int i = blockIdx.x * 256 + threadIdx.x;
    if (i < HW_) {
        float s = 0.f;
        for (int r = 0; r < 32; ++r) s += partial[(size_t)r * HW_ + i];
        ninv[i] = rsqrtf(s);
    }
}

// ---------------------------------------------------------------------------
// 2) transpose + normalize + split: x [B,C,HW] -> xn planes [B,HW,C] bf16 hi/lo
// ---------------------------------------------------------------------------
__global__ void k_transpose(const float* __restrict__ x, const float* __restrict__ ninv,
                            u16* __restrict__ obH, u16* __restrict__ obL) {
    __shared__ float tile[32][33];
    int b  = blockIdx.z;
    int m0 = blockIdx.x * 32, c0 = blockIdx.y * 32;
    int tx = threadIdx.x, ty = threadIdx.y;
    const float* xb = x + (size_t)b * C_ * HW_;
    #pragma unroll
    for (int j = 0; j < 32; j += 8)
        tile[ty + j][tx] = xb[(size_t)(c0 + ty + j) * HW_ + m0 + tx];
    __syncthreads();
    size_t base = (size_t)b * HW_ * C_;
    #pragma unroll
    for (int j = 0; j < 32; j += 8) {
        int m = m0 + ty + j;
        unsigned pk = pack_hilo(tile[tx][ty + j] * ninv[m]);
        size_t idx = base + (size_t)m * C_ + c0 + tx;
        obH[idx] = (u16)(pk >> 16);
        obL[idx] = (u16)pk;
    }
}

// ---------------------------------------------------------------------------
// 3) weight prep
// ---------------------------------------------------------------------------
__global__ void k_packW(const float* __restrict__ in, u16* __restrict__ oh,
                        u16* __restrict__ ol) {
    size_t i = (size_t)blockIdx.x * 256 + threadIdx.x;
    unsigned pk = pack_hilo(in[i]);
    oh[i] = (u16)(pk >> 16); ol[i] = (u16)pk;
}
__global__ void k_packFG(const float* __restrict__ fW, const float* __restrict__ gW,
                         const float* __restrict__ fb, const float* __restrict__ gb,
                         u16* __restrict__ oh, u16* __restrict__ ol,
                         float* __restrict__ fgb) {
    int idx = blockIdx.x * 256 + threadIdx.x;   // 65536
    int row = idx >> 9, c = idx & 511;
    float v = (row < 64) ? fW[row * 512 + c] : gW[(row - 64) * 512 + c];
    unsigned pk = pack_hilo(v);
    oh[idx] = (u16)(pk >> 16); ol[idx] = (u16)pk;
    if (idx < 128) fgb[idx] = (idx < 64) ? fb[idx] : gb[idx - 64];
}

// ---------------------------------------------------------------------------
// 4) unified planar bf16 MFMA GEMM: C = A[M,K] * B[N,K]^T
//    128x128 tile, BK=32, 4 waves, SINGLE-BUFFER 2-barrier loop (r4-proven:
//    explicit dbuf pipelining regressed 40% in r5 — compiler drains vmcnt(0)
//    before ds_reads it can't prove independent; multi-wave overlap does the
//    hiding instead, m114).
//    LDS swizzle (verified r3/r4): chunk li: rp=li*8+(lane>>3),
//    gg=(lane&7)^(rp&7), r=rp*2+(gg>>2), kc=k0+(gg&3)*8; fragment: rp=r>>1,
//    gg=((r&1)<<2)+g, off=rp*64+((gg^(rp&7))<<3).
//    EPI 0: Cf fp32 = acc
//    EPI 1: planar hi/lo = acc + bias[row]
//    EPI 2: Ch = bf16(scale*acc + compose(Ch,Cl))   (in-place fdd)
//    EPI 3: planar hi/lo = acc + bias[col]
//    EPI 4: Ch = bf16(acc)
//    EPI 5: Ch = bf16(acc + bias[row])
// ---------------------------------------------------------------------------
template<int PERMB, int SPLITA, int SPLITB, int EPI>
__global__ __launch_bounds__(256) void k_gemm(
    const u16* __restrict__ Ah, const u16* __restrict__ Al,
    const u16* __restrict__ Bh, const u16* __restrict__ Bl,
    const float* __restrict__ bias,
    float* __restrict__ Cf, u16* __restrict__ Ch, u16* __restrict__ Cl,
    const float* __restrict__ scaleP,
    int N, int K, int lda, int ldb, long sA, long sB, long sC)
{
    constexpr int PLANES = 2 + SPLITA + SPLITB;
    constexpr int CPW = 2 * PLANES;             // staging chunks per wave
    __shared__ u16 lds[PLANES * 4096];

    const int b = blockIdx.z;
    const u16* pAh = Ah + (size_t)b * sA;
    const u16* pAl = SPLITA ? Al + (size_t)b * sA : nullptr;
    const u16* pBh = Bh + (size_t)b * sB;
    const u16* pBl = SPLITB ? Bl + (size_t)b * sB : nullptr;
    const int m0 = blockIdx.y * 128, n0 = blockIdx.x * 128;
    const int tid = threadIdx.x, wave = tid >> 6, lane = tid & 63;
    const int wm = wave >> 1, wn = wave & 1;
    const int g = lane >> 4;

    f32x4 acc[4][4];
    #pragma unroll
    for (int i = 0; i < 4; ++i)
        #pragma unroll
        for (int j = 0; j < 4; ++j) { f32x4 z = {0.f,0.f,0.f,0.f}; acc[i][j] = z; }

    for (int kt = 0; kt < (K >> 5); ++kt) {
        const int k0 = kt << 5;
        __syncthreads();
        #pragma unroll
        for (int q = 0; q < CPW; ++q) {
            int ci = wave * CPW + q;
            int pl = ci >> 3, li = ci & 7;
            bool isA = pl < (1 + SPLITA);
            const u16* gp;
            int lbase;
            if (pl == 0)                      { gp = pAh; lbase = 0; }
            else if (SPLITA && pl == 1)       { gp = pAl; lbase = 4096; }
            else if (pl == 1 + SPLITA)        { gp = pBh; lbase = (1 + SPLITA) * 4096; }
            else                              { gp = pBl; lbase = (2 + SPLITA) * 4096; }
            int ld = isA ? lda : ldb;
            int rb = isA ? m0 : n0;
            int rp = li * 8 + (lane >> 3);
            int gg = (lane & 7) ^ (rp & 7);
            int r  = rp * 2 + (gg >> 2);
            int kc = k0 + (gg & 3) * 8;
            int rowg = rb + r;
            if (PERMB && !isA) rowg = ((rowg & 31) << 5) | (rowg >> 5);
            gld16(gp + (size_t)rowg * ld + kc, lds + lbase + li * 512 + lane * 8);
        }
        __syncthreads();

        const u16* AsH = lds;
        const u16* AsL = lds + 4096;
        const u16* BsH = lds + (1 + SPLITA) * 4096;
        const u16* BsL = lds + (2 + SPLITA) * 4096;

        short8v ah[4], alv[4];
        #pragma unroll
        for (int i = 0; i < 4; ++i) {
            int r = wm * 64 + i * 16 + (lane & 15);
            int rp = r >> 1, gg = ((r & 1) << 2) + g;
            int off = rp * 64 + ((gg ^ (rp & 7)) << 3);
            ah[i] = *(const short8v*)(AsH + off);
            if (SPLITA) alv[i] = *(const short8v*)(AsL + off);
        }
        #pragma unroll
        for (int j = 0; j < 4; ++j) {
            int r = wn * 64 + j * 16 + (lane & 15);
            int rp = r >> 1, gg = ((r & 1) << 2) + g;
            int off = rp * 64 + ((gg ^ (rp & 7)) << 3);
            short8v bh = *(const short8v*)(BsH + off);
            short8v bl;
            if (SPLITB) bl = *(const short8v*)(BsL + off);
            #pragma unroll
            for (int i = 0; i < 4; ++i) {
                acc[i][j] = __builtin_amdgcn_mfma_f32_16x16x32_bf16(ah[i], bh, acc[i][j], 0, 0, 0);
                if (SPLITB)
                    acc[i][j] = __builtin_amdgcn_mfma_f32_16x16x32_bf16(ah[i], bl, acc[i][j], 0, 0, 0);
                if (SPLITA)
                    acc[i][j] = __builtin_amdgcn_mfma_f32_16x16x32_bf16(alv[i], bh, acc[i][j], 0, 0, 0);
            }
        }
    }

    const float sc = (EPI == 2) ? scaleP[0] : 0.f;
    const int colbase = n0 + wn * 64 + (lane & 15);
    const int rowbase = m0 + wm * 64 + ((lane >> 4) << 2);
    #pragma unroll
    for (int i = 0; i < 4; ++i)
        #pragma unroll
        for (int j = 0; j < 4; ++j) {
            int col = colbase + j * 16;
            #pragma unroll
            for (int rg = 0; rg < 4; ++rg) {
                int row = rowbase + i * 16 + rg;
                size_t idx = (size_t)b * sC + (size_t)row * N + col;
                float a = acc[i][j][rg];
                if (EPI == 0) {
                    Cf[idx] = a;
                } else if (EPI == 1 || EPI == 3) {
                    float v = a + ((EPI == 1) ? bias[row] : bias[col]);
                    unsigned pk = pack_hilo(v);
                    Ch[idx] = (u16)(pk >> 16); Cl[idx] = (u16)pk;
                } else if (EPI == 2) {
                    float v = sc * a + compose_hilo(Ch[idx], Cl[idx]);
                    Ch[idx] = tobf(v);
                } else if (EPI == 4) {
                    Ch[idx] = tobf(a);
                } else {   // EPI == 5
                    Ch[idx] = tobf(a + bias[row]);
                }
            }
        }
}

// ---------------------------------------------------------------------------
// 5) row softmax on bf16 S, u16 in-place
// ---------------------------------------------------------------------------
__global__ __launch_bounds__(256) void k_softmax(u16* __restrict__ S) {
    size_t row = blockIdx.x;
    u16* r = S + row * (size_t)HW_;
    int t = threadIdx.x;
    ushort4 raw = ((const ushort4*)r)[t];
    float v0 = frombf(raw.x), v1 = frombf(raw.y), v2 = frombf(raw.z), v3 = frombf(raw.w);

    __shared__ float redm[4], reds[4];
    int wid = t >> 6, lane = t & 63;

    float m = fmaxf(fmaxf(v0, v1), fmaxf(v2, v3));
    for (int o = 32; o > 0; o >>= 1) m = fmaxf(m, __shfl_down(m, o));
    if (lane == 0) redm[wid] = m;
    __syncthreads();
    if (t == 0) redm[0] = fmaxf(fmaxf(redm[0], redm[1]), fmaxf(redm[2], redm[3]));
    __syncthreads();
    m = redm[0];

    v0 = expf(v0 - m); v1 = expf(v1 - m); v2 = expf(v2 - m); v3 = expf(v3 - m);
    float s = v0 + v1 + v2 + v3;
    for (int o = 32; o > 0; o >>= 1) s += __shfl_down(s, o);
    if (lane == 0) reds[wid] = s;
    __syncthreads();
    if (t == 0) reds[0] = reds[0] + reds[1] + reds[2] + reds[3];
    __syncthreads();
    float inv = 1.f / reds[0];
    ushort4 o4;
    o4.x = tobf(v0 * inv); o4.y = tobf(v1 * inv);
    o4.z = tobf(v2 * inv); o4.w = tobf(v3 * inv);
    ((ushort4*)r)[t] = o4;
}

// ---------------------------------------------------------------------------
// 6) single-plane u16 transpose of fdd flat view [512][1024] -> fddT [1024][512]
// ---------------------------------------------------------------------------
__global__ void k_tposeU1(const u16* __restrict__ src, u16* __restrict__ dst) {
    __shared__ u16 tile[32][33];
    int b = blockIdx.z;
    const u16* sb = src + (size_t)b * (C_ * HW_);
    u16* db = dst + (size_t)b * (C_ * HW_);
    int c0 = blockIdx.x * 32, r0 = blockIdx.y * 32;     // src [512 r][1024 c]
    int tx = threadIdx.x, ty = threadIdx.y;
    #pragma unroll
    for (int j = 0; j < 32; j += 8)
        tile[ty + j][tx] = sb[(size_t)(r0 + ty + j) * HW_ + c0 + tx];
    __syncthreads();
    #pragma unroll
    for (int j = 0; j < 32; j += 8)
        db[(size_t)(c0 + ty + j) * C_ + r0 + tx] = tile[tx][ty + j];
}

// ---------------------------------------------------------------------------
// 7) top-48: tau-prune + compact + sort (verified r3/r4)
// ---------------------------------------------------------------------------
__device__ __forceinline__ float sort64_desc(float v, int lane) {
    #pragma unroll
    for (int k = 2; k <= 64; k <<= 1) {
        #pragma unroll
        for (int j = k >> 1; j > 0; j >>= 1) {
            float o = __shfl_xor(v, j);
            bool takeMax = (((lane & k) == 0) == ((lane & j) == 0));
            v = takeMax ? fmaxf(v, o) : fminf(v, o);
        }
    }
    return v;
}
__device__ __forceinline__ float bmerge64_desc(float a, float b, int lane) {
    float br = __shfl(b, 63 - lane);
    float c = fmaxf(a, br);
    #pragma unroll
    for (int j = 32; j > 0; j >>= 1) {
        float o = __shfl_xor(c, j);
        c = ((lane & j) == 0) ? fmaxf(c, o) : fminf(c, o);
    }
    return c;
}

__global__ __launch_bounds__(256) void k_topk(const float* __restrict__ corr,
                                              float* __restrict__ topv) {
    int row = blockIdx.x, tid = threadIdx.x, wave = tid >> 6, lane = tid & 63;
    const float4 e = ((const float4*)(corr + (size_t)row * HW_))[tid];
    float gm = fmaxf(fmaxf(e.x, e.y), fmaxf(e.z, e.w));
    float v = sort64_desc(gm, lane);

    __shared__ float ls[4][64];
    __shared__ float tau_s;
    __shared__ int cnt_s;
    __shared__ float buf[1024];
    ls[wave][lane] = v;
    buf[tid] = -INFINITY; buf[tid + 256] = -INFINITY;
    buf[tid + 512] = -INFINITY; buf[tid + 768] = -INFINITY;
    if (tid == 0) cnt_s = 0;
    __syncthreads();

    if (wave == 0) {
        float ab = bmerge64_desc(ls[0][lane], ls[1][lane], lane);
        float cd = bmerge64_desc(ls[2][lane], ls[3][lane], lane);
        float t  = bmerge64_desc(ab, cd, lane);
        if (lane == T_ - 1) tau_s = t;
    }
    __syncthreads();
    float tau = tau_s;

    int c = (e.x >= tau) + (e.y >= tau) + (e.z >= tau) + (e.w >= tau);
    int off = 0;
    if (c) off = atomicAdd(&cnt_s, c);
    if (e.x >= tau) buf[off++] = e.x;
    if (e.y >= tau) buf[off++] = e.y;
    if (e.z >= tau) buf[off++] = e.z;
    if (e.w >= tau) buf[off++] = e.w;
    __syncthreads();
    int cnt = cnt_s;

    if (cnt <= 128) {
        if (wave == 0) {
            float a  = sort64_desc(buf[lane], lane);
            float b2 = sort64_desc(buf[64 + lane], lane);
            float br = __shfl(b2, 63 - lane);
            float hi = fmaxf(a, br);
            #pragma unroll
            for (int j = 32; j > 0; j >>= 1) {
                float o = __shfl_xor(hi, j);
                hi = ((lane & j) == 0) ? fmaxf(hi, o) : fminf(hi, o);
            }
            if (lane < T_) topv[(size_t)row * T_ + lane] = fmaxf(hi, 0.f);
        }
    } else {
        int P = 256; while (P < cnt) P <<= 1;
        for (int k = 2; k <= P; k <<= 1)
            for (int j = k >> 1; j > 0; j >>= 1) {
                for (int t2 = tid; t2 < P; t2 += 256) {
                    int ixj = t2 ^ j;
                    if (ixj > t2) {
                        float a = buf[t2], b3 = buf[ixj];
                        bool desc = ((t2 & k) == 0);
                        if (desc ? (a < b3) : (a > b3)) { buf[t2] = b3; buf[ixj] = a; }
                    }
                }
                __syncthreads();
            }
        if (tid < T_) topv[(size_t)row * T_ + tid] = fmaxf(buf[tid], 0.f);
    }
}

// ---------------------------------------------------------------------------
// 8) column norm over (B,H) and final transpose
// ---------------------------------------------------------------------------
__global__ void k_colss(const float* __restrict__ topv, float* __restrict__ colss) {
    int o = blockIdx.x;
    int w = o / T_, t = o % T_;
    int lane = threadIdx.x;
    float s = 0.f;
    for (int i = lane; i < 512; i += 64) {
        int b = i >> 5, h = i & 31;
        float v = topv[(size_t)((b << 10) + (h << 5) + w) * T_ + t];
        s += v * v;
    }
    for (int off = 32; off > 0; off >>= 1) s += __shfl_down(s, off);
    if (lane == 0) colss[o] = s;
}

__global__ void k_final(const float* __restrict__ topv, const float* __restrict__ colss,
                        float* __restrict__ out) {
    int idx = blockIdx.x * 256 + threadIdx.x;
    if (idx >= B_ * T_ * HW_) return;
    int w = idx & 31;
    int h = (idx >> 5) & 31;
    int t = (idx >> 10) % T_;
    int b = idx / (T_ * HW_);
    float v = topv[(size_t)((b << 10) + (h << 5) + w) * T_ + t];
    out[idx] = v * rsqrtf(colss[w * T_ + t]);
}

// ---------------------------------------------------------------------------
extern "C" void kernel_launch(void* const* d_in, const int* in_sizes, int n_in,
                              void* d_out, int out_size, void* d_ws, size_t ws_size,
                              hipStream_t stream) {
    const float* x     = (const float*)d_in[0];
    const float* fW    = (const float*)d_in[1];
    const float* fb    = (const float*)d_in[2];
    const float* gW    = (const float*)d_in[3];
    const float* gb    = (const float*)d_in[4];
    const float* hW    = (const float*)d_in[5];
    const float* hb    = (const float*)d_in[6];
    const float* scale = (const float*)d_in[7];
    float* out = (float*)d_out;

    // byte-offset workspace layout (~144 MB, proven available)
    char* wsb = (char*)d_ws;
    float* part = (float*)(wsb + 0);                 // 131072 B
    float* ninv = (float*)(wsb + 131072);            // 4096 B
    u16*   hWh  = (u16*)(wsb + 135168);              // 524288 B
    u16*   hWl  = (u16*)(wsb + 659456);              // 524288 B (unused)
    u16*   fgWh = (u16*)(wsb + 1183744);             // 131072 B
    u16*   fgWl = (u16*)(wsb + 1314816);             // 131072 B
    float* fgb  = (float*)(wsb + 1445888);           // 512 B
    u16*   xnH  = (u16*)(wsb + 1446400);             // 16777216 B (xn hi -> fdd bf16)
    u16*   xnL  = (u16*)(wsb + 18223616);            // 16777216 B (xn lo)
    u16*   fgH  = (u16*)(wsb + 35000832);            // 4194304 B (later topv)
    u16*   fgL  = (u16*)(wsb + 39195136);            // 4194304 B (later colss)
    u16*   hvTH = (u16*)(wsb + 43389440);            // 16777216 B (hv bf16 -> fddT)
    u16*   hvTL = (u16*)(wsb + 60166656);            // 16777216 B (unused)
    float* S    = (float*)(wsb + 76943872);          // 67108864 B (S/P u16 -> corr fp32)
    float* topv = (float*)fgH;
    float* colss= (float*)fgL;
    u16*   Sp   = (u16*)S;                           // u16 S/P view [B*1024][1024]

    const long sXn = 524288;    // [1024][512] elements per batch
    const long sFG = 131072;    // [1024][128]
    const long sS  = 1048576;   // [1024][1024]

    // 1) per-pixel Frobenius norm
    k_colsq<<<128, 256, 0, stream>>>(x, part);
    k_rsqrt<<<4, 256, 0, stream>>>(part, ninv);

    // 2) normalized channel-last bf16-split planes
    k_transpose<<<dim3(32, 16, 16), dim3(32, 8), 0, stream>>>(x, ninv, xnH, xnL);

    // 3) weight planes
    k_packW<<<1024, 256, 0, stream>>>(hW, hWh, hWl);
    k_packFG<<<256, 256, 0, stream>>>(fW, gW, fb, gb, fgWh, fgWl, fgb);

    // 4) fg = xn @ [fW|gW]^T + bias[col]  (3-term, planar out [B,1024,128])
    k_gemm<0, 1, 1, 3><<<dim3(1, 8, 16), 256, 0, stream>>>(
        xnH, xnL, fgWh, fgWl, fgb, nullptr, fgH, fgL, nullptr,
        128, 512, 512, 512, sXn, 0, sFG);

    // 5) hv = hW @ xn^T + hb[row], 2-term (hW hi only), single bf16 plane out
    k_gemm<0, 0, 1, 5><<<dim3(8, 4, 16), 256, 0, stream>>>(
        hWh, nullptr, xnH, xnL, hb, nullptr, hvTH, nullptr, nullptr,
        1024, 512, 512, 512, 0, sXn, sXn);

    // 6) S = f @ perm(g)^T  (3-term, K=64, W-major keys) -> bf16 u16
    k_gemm<1, 1, 1, 4><<<dim3(8, 8, 16), 256, 0, stream>>>(
        fgH, fgL, fgH + 64, fgL + 64, nullptr, nullptr, Sp, nullptr, nullptr,
        1024, 64, 128, 128, sFG, sFG, sS);

    // 7) softmax rows, u16 in place -> P bf16
    k_softmax<<<B_ * HW_, 256, 0, stream>>>(Sp);

    // 8) fdd = bf16(scale*(P @ hv^T) + xn), 1-term, in place over xnH
    k_gemm<0, 0, 0, 2><<<dim3(4, 8, 16), 256, 0, stream>>>(
        Sp, nullptr, hvTH, nullptr, nullptr, nullptr, xnH, xnL, scale,
        512, 1024, 1024, 1024, sS, sXn, sXn);

    // 9) fddT: transpose flat [512][1024] view of fddH -> hvTH [1024][512]
    k_tposeU1<<<dim3(32, 16, 16), dim3(32, 8), 0, stream>>>(xnH, hvTH);

    // 10) corr = fdd @ fddT^T (1-term bf16) -> fp32 into S
    k_gemm<0, 0, 0, 0><<<dim3(8, 8, 16), 256, 0, stream>>>(
        xnH, nullptr, hvTH, nullptr, nullptr, S, nullptr, nullptr, nullptr,
        1024, 512, 512, 512, sXn, sXn, sS);

    // 11) top-48 desc + relu
    k_topk<<<B_ * HW_, 256, 0, stream>>>(S, topv);

    // 12) norm over (B,H) + output transpose
    k_colss<<<W_ * T_, 64, 0, stream>>>(topv, colss);
    k_final<<<(B_ * T_ * HW_ + 255) / 256, 256, 0, stream>>>(topv, colss, out);
}

// Round 7
// 218.166 us; speedup vs baseline: 1.8579x; 1.2033x over previous
//
#include <hip/hip_runtime.h>
#include <cstdint>
#include <cstddef>

#define B_   16
#define C_   512
#define H_   32
#define W_   32
#define HW_  1024
#define TC_  64
#define T_   48

typedef unsigned short u16;
typedef __attribute__((ext_vector_type(8))) short short8v;
typedef __attribute__((ext_vector_type(4))) float f32x4;

// ---------------------------------------------------------------------------
// bf16 helpers
// ---------------------------------------------------------------------------
__device__ __forceinline__ u16 tobf(float x) {
    unsigned u = __float_as_uint(x);
    return (u16)((u + 0x7FFFu + ((u >> 16) & 1u)) >> 16);    // RTNE
}
__device__ __forceinline__ float frombf(u16 h) {
    return __uint_as_float(((unsigned)h) << 16);
}

__device__ __forceinline__ void gld16(const void* g, void* l) {
    __builtin_amdgcn_global_load_lds(
        (const __attribute__((address_space(1))) void*)g,
        (__attribute__((address_space(3))) void*)l, 16, 0, 0);
}

// ---------------------------------------------------------------------------
// 1) Frobenius-norm helpers
// ---------------------------------------------------------------------------
__global__ void k_colsq(const float* __restrict__ x, float* __restrict__ partial) {
    int bid = blockIdx.x;
    int col = (bid & 3) * 256 + threadIdx.x;
    int r0  = (bid >> 2) * 256;
    const float* p = x + (size_t)r0 * HW_ + col;
    float s = 0.f;
    for (int r = 0; r < 256; ++r) { float v = p[(size_t)r * HW_]; s += v * v; }
    partial[(size_t)(bid >> 2) * HW_ + col] = s;
}

__global__ void k_rsqrt(const float* __restrict__ partial, float* __restrict__ ninv) {
    int i = blockIdx.x * 256 + threadIdx.x;
    if (i < HW_) {
        float s = 0.f;
        for (int r = 0; r < 32; ++r) s += partial[(size_t)r * HW_ + i];
        ninv[i] = rsqrtf(s);
    }
}

// ---------------------------------------------------------------------------
// 2) transpose + normalize: x [B,C,HW] -> xnH bf16 [B,HW,C]
// ---------------------------------------------------------------------------
__global__ void k_transpose(const float* __restrict__ x, const float* __restrict__ ninv,
                            u16* __restrict__ obH) {
    __shared__ float tile[32][33];
    int b  = blockIdx.z;
    int m0 = blockIdx.x * 32, c0 = blockIdx.y * 32;
    int tx = threadIdx.x, ty = threadIdx.y;
    const float* xb = x + (size_t)b * C_ * HW_;
    #pragma unroll
    for (int j = 0; j < 32; j += 8)
        tile[ty + j][tx] = xb[(size_t)(c0 + ty + j) * HW_ + m0 + tx];
    __syncthreads();
    size_t base = (size_t)b * HW_ * C_;
    #pragma unroll
    for (int j = 0; j < 32; j += 8) {
        int m = m0 + ty + j;
        obH[base + (size_t)m * C_ + c0 + tx] = tobf(tile[tx][ty + j] * ninv[m]);
    }
}

// ---------------------------------------------------------------------------
// 3) weight prep (hi plane only)
// ---------------------------------------------------------------------------
__global__ void k_packW(const float* __restrict__ in, u16* __restrict__ oh) {
    size_t i = (size_t)blockIdx.x * 256 + threadIdx.x;
    oh[i] = tobf(in[i]);
}
__global__ void k_packFG(const float* __restrict__ fW, const float* __restrict__ gW,
                         const float* __restrict__ fb, const float* __restrict__ gb,
                         u16* __restrict__ oh, float* __restrict__ fgb) {
    int idx = blockIdx.x * 256 + threadIdx.x;   // 65536
    int row = idx >> 9, c = idx & 511;
    float v = (row < 64) ? fW[row * 512 + c] : gW[(row - 64) * 512 + c];
    oh[idx] = tobf(v);
    if (idx < 128) fgb[idx] = (idx < 64) ? fb[idx] : gb[idx - 64];
}

// ---------------------------------------------------------------------------
// 4a) 1-term bf16 MFMA GEMM, 128x128 tile, 4 waves, KU-unrolled K (KU k-tiles
//     staged per barrier pair; same synchronous structure proven r4/r6).
//     LDS swizzle (verified r3-r6): chunk li: rp=li*8+(lane>>3),
//     gg=(lane&7)^(rp&7), r=rp*2+(gg>>2), kc=k0+(gg&3)*8; fragment: rp=r>>1,
//     gg=((r&1)<<2)+g, off=rp*64+((gg^(rp&7))<<3).
//     EPI 0: Cf fp32 = acc
//     EPI 2: Ch = bf16(scale*acc + frombf(Ch))   (in-place fdd over xnH)
//     EPI 4: Ch = bf16(acc)
//     EPI 5: Ch = bf16(acc + bias[row])
//     EPI 6: Ch = bf16(acc + bias[col])
// ---------------------------------------------------------------------------
template<int PERMB, int EPI, int KU>
__global__ __launch_bounds__(256) void k_gemm1(
    const u16* __restrict__ A, const u16* __restrict__ Bm,
    const float* __restrict__ bias,
    float* __restrict__ Cf, u16* __restrict__ Ch,
    const float* __restrict__ scaleP,
    int N, int K, int lda, int ldb, long sA, long sB, long sC)
{
    __shared__ u16 lds[8192 * KU];              // per u: A 4096 u16, B 4096 u16
    const int b = blockIdx.z;
    const u16* pA = A + (size_t)b * sA;
    const u16* pB = Bm + (size_t)b * sB;
    const int m0 = blockIdx.y * 128, n0 = blockIdx.x * 128;
    const int tid = threadIdx.x, wave = tid >> 6, lane = tid & 63;
    const int wm = wave >> 1, wn = wave & 1;
    const int g = lane >> 4;

    f32x4 acc[4][4];
    #pragma unroll
    for (int i = 0; i < 4; ++i)
        #pragma unroll
        for (int j = 0; j < 4; ++j) { f32x4 z = {0.f,0.f,0.f,0.f}; acc[i][j] = z; }

    for (int kt = 0; kt < (K >> 5); kt += KU) {
        __syncthreads();
        #pragma unroll
        for (int u = 0; u < KU; ++u) {
            const int k0 = (kt + u) << 5;
            u16* lb = lds + u * 8192;
            #pragma unroll
            for (int q = 0; q < 4; ++q) {
                int ci = wave * 4 + q;          // 16 chunks: 0-7 A, 8-15 B
                bool isA = ci < 8;
                int li = ci & 7;
                const u16* gp = isA ? pA : pB;
                int ld = isA ? lda : ldb;
                int rb = isA ? m0 : n0;
                int rp = li * 8 + (lane >> 3);
                int gg = (lane & 7) ^ (rp & 7);
                int r  = rp * 2 + (gg >> 2);
                int kc = k0 + (gg & 3) * 8;
                int rowg = rb + r;
                if (PERMB && !isA) rowg = ((rowg & 31) << 5) | (rowg >> 5);
                gld16(gp + (size_t)rowg * ld + kc,
                      lb + (isA ? 0 : 4096) + li * 512 + lane * 8);
            }
        }
        __syncthreads();
        #pragma unroll
        for (int u = 0; u < KU; ++u) {
            const u16* As = lds + u * 8192;
            const u16* Bs = As + 4096;
            short8v av[4];
            #pragma unroll
            for (int i = 0; i < 4; ++i) {
                int r = wm * 64 + i * 16 + (lane & 15);
                int rp = r >> 1, gg = ((r & 1) << 2) + g;
                av[i] = *(const short8v*)(As + rp * 64 + ((gg ^ (rp & 7)) << 3));
            }
            #pragma unroll
            for (int j = 0; j < 4; ++j) {
                int r = wn * 64 + j * 16 + (lane & 15);
                int rp = r >> 1, gg = ((r & 1) << 2) + g;
                short8v bv = *(const short8v*)(Bs + rp * 64 + ((gg ^ (rp & 7)) << 3));
                #pragma unroll
                for (int i = 0; i < 4; ++i)
                    acc[i][j] = __builtin_amdgcn_mfma_f32_16x16x32_bf16(av[i], bv, acc[i][j], 0, 0, 0);
            }
        }
    }

    const float sc = (EPI == 2) ? scaleP[0] : 0.f;
    const int colbase = n0 + wn * 64 + (lane & 15);
    const int rowbase = m0 + wm * 64 + ((lane >> 4) << 2);
    #pragma unroll
    for (int i = 0; i < 4; ++i)
        #pragma unroll
        for (int j = 0; j < 4; ++j) {
            int col = colbase + j * 16;
            #pragma unroll
            for (int rg = 0; rg < 4; ++rg) {
                int row = rowbase + i * 16 + rg;
                size_t idx = (size_t)b * sC + (size_t)row * N + col;
                float a = acc[i][j][rg];
                if (EPI == 0)      Cf[idx] = a;
                else if (EPI == 2) Ch[idx] = tobf(sc * a + frombf(Ch[idx]));
                else if (EPI == 4) Ch[idx] = tobf(a);
                else if (EPI == 5) Ch[idx] = tobf(a + bias[row]);
                else               Ch[idx] = tobf(a + bias[col]);   // EPI 6
            }
        }
}

// ---------------------------------------------------------------------------
// 4b) 1-term bf16 MFMA GEMM, 128x256 tile, 8 waves, KU-unrolled.
//     Wave (wm=wave>>2, wn=wave&3) owns a 64x64 sub-tile. Same swizzle.
// ---------------------------------------------------------------------------
template<int PERMB, int EPI, int KU>
__global__ __launch_bounds__(512) void k_gemm2(
    const u16* __restrict__ A, const u16* __restrict__ Bm,
    const float* __restrict__ bias,
    float* __restrict__ Cf, u16* __restrict__ Ch,
    const float* __restrict__ scaleP,
    int N, int K, int lda, int ldb, long sA, long sB, long sC)
{
    __shared__ u16 lds[12288 * KU];             // per u: A 4096 u16, B 8192 u16
    const int b = blockIdx.z;
    const u16* pA = A + (size_t)b * sA;
    const u16* pB = Bm + (size_t)b * sB;
    const int m0 = blockIdx.y * 128, n0 = blockIdx.x * 256;
    const int tid = threadIdx.x, wave = tid >> 6, lane = tid & 63;
    const int wm = wave >> 2, wn = wave & 3;
    const int g = lane >> 4;

    f32x4 acc[4][4];
    #pragma unroll
    for (int i = 0; i < 4; ++i)
        #pragma unroll
        for (int j = 0; j < 4; ++j) { f32x4 z = {0.f,0.f,0.f,0.f}; acc[i][j] = z; }

    for (int kt = 0; kt < (K >> 5); kt += KU) {
        __syncthreads();
        #pragma unroll
        for (int u = 0; u < KU; ++u) {
            const int k0 = (kt + u) << 5;
            u16* lb = lds + u * 12288;
            #pragma unroll
            for (int q = 0; q < 3; ++q) {
                int ci = wave * 3 + q;          // 24 chunks: 0-7 A, 8-23 B
                bool isA = ci < 8;
                int li = isA ? ci : ci - 8;
                const u16* gp = isA ? pA : pB;
                int ld = isA ? lda : ldb;
                int rb = isA ? m0 : n0;
                int rp = li * 8 + (lane >> 3);
                int gg = (lane & 7) ^ (rp & 7);
                int r  = rp * 2 + (gg >> 2);
                int kc = k0 + (gg & 3) * 8;
                int rowg = rb + r;
                if (PERMB && !isA) rowg = ((rowg & 31) << 5) | (rowg >> 5);
                gld16(gp + (size_t)rowg * ld + kc,
                      lb + (isA ? 0 : 4096) + li * 512 + lane * 8);
            }
        }
        __syncthreads();
        #pragma unroll
        for (int u = 0; u < KU; ++u) {
            const u16* As = lds + u * 12288;
            const u16* Bs = As + 4096;
            short8v av[4];
            #pragma unroll
            for (int i = 0; i < 4; ++i) {
                int r = wm * 64 + i * 16 + (lane & 15);
                int rp = r >> 1, gg = ((r & 1) << 2) + g;
                av[i] = *(const short8v*)(As + rp * 64 + ((gg ^ (rp & 7)) << 3));
            }
            #pragma unroll
            for (int j = 0; j < 4; ++j) {
                int r = wn * 64 + j * 16 + (lane & 15);
                int rp = r >> 1, gg = ((r & 1) << 2) + g;
                short8v bv = *(const short8v*)(Bs + rp * 64 + ((gg ^ (rp & 7)) << 3));
                #pragma unroll
                for (int i = 0; i < 4; ++i)
                    acc[i][j] = __builtin_amdgcn_mfma_f32_16x16x32_bf16(av[i], bv, acc[i][j], 0, 0, 0);
            }
        }
    }

    const float sc = (EPI == 2) ? scaleP[0] : 0.f;
    const int colbase = n0 + wn * 64 + (lane & 15);
    const int rowbase = m0 + wm * 64 + ((lane >> 4) << 2);
    #pragma unroll
    for (int i = 0; i < 4; ++i)
        #pragma unroll
        for (int j = 0; j < 4; ++j) {
            int col = colbase + j * 16;
            #pragma unroll
            for (int rg = 0; rg < 4; ++rg) {
                int row = rowbase + i * 16 + rg;
                size_t idx = (size_t)b * sC + (size_t)row * N + col;
                float a = acc[i][j][rg];
                if (EPI == 0)      Cf[idx] = a;
                else if (EPI == 2) Ch[idx] = tobf(sc * a + frombf(Ch[idx]));
                else if (EPI == 4) Ch[idx] = tobf(a);
                else if (EPI == 5) Ch[idx] = tobf(a + bias[row]);
                else               Ch[idx] = tobf(a + bias[col]);
            }
        }
}

// ---------------------------------------------------------------------------
// 5) row softmax on bf16 S, u16 in-place
// ---------------------------------------------------------------------------
__global__ __launch_bounds__(256) void k_softmax(u16* __restrict__ S) {
    size_t row = blockIdx.x;
    u16* r = S + row * (size_t)HW_;
    int t = threadIdx.x;
    ushort4 raw = ((const ushort4*)r)[t];
    float v0 = frombf(raw.x), v1 = frombf(raw.y), v2 = frombf(raw.z), v3 = frombf(raw.w);

    __shared__ float redm[4], reds[4];
    int wid = t >> 6, lane = t & 63;

    float m = fmaxf(fmaxf(v0, v1), fmaxf(v2, v3));
    for (int o = 32; o > 0; o >>= 1) m = fmaxf(m, __shfl_down(m, o));
    if (lane == 0) redm[wid] = m;
    __syncthreads();
    if (t == 0) redm[0] = fmaxf(fmaxf(redm[0], redm[1]), fmaxf(redm[2], redm[3]));
    __syncthreads();
    m = redm[0];

    v0 = expf(v0 - m); v1 = expf(v1 - m); v2 = expf(v2 - m); v3 = expf(v3 - m);
    float s = v0 + v1 + v2 + v3;
    for (int o = 32; o > 0; o >>= 1) s += __shfl_down(s, o);
    if (lane == 0) reds[wid] = s;
    __syncthreads();
    if (t == 0) reds[0] = reds[0] + reds[1] + reds[2] + reds[3];
    __syncthreads();
    float inv = 1.f / reds[0];
    ushort4 o4;
    o4.x = tobf(v0 * inv); o4.y = tobf(v1 * inv);
    o4.z = tobf(v2 * inv); o4.w = tobf(v3 * inv);
    ((ushort4*)r)[t] = o4;
}

// ---------------------------------------------------------------------------
// 6) single-plane u16 transpose of fdd flat view [512][1024] -> fddT [1024][512]
// ---------------------------------------------------------------------------
__global__ void k_tposeU1(const u16* __restrict__ src, u16* __restrict__ dst) {
    __shared__ u16 tile[32][33];
    int b = blockIdx.z;
    const u16* sb = src + (size_t)b * (C_ * HW_);
    u16* db = dst + (size_t)b * (C_ * HW_);
    int c0 = blockIdx.x * 32, r0 = blockIdx.y * 32;
    int tx = threadIdx.x, ty = threadIdx.y;
    #pragma unroll
    for (int j = 0; j < 32; j += 8)
        tile[ty + j][tx] = sb[(size_t)(r0 + ty + j) * HW_ + c0 + tx];
    __syncthreads();
    #pragma unroll
    for (int j = 0; j < 32; j += 8)
        db[(size_t)(c0 + ty + j) * C_ + r0 + tx] = tile[tx][ty + j];
}

// ---------------------------------------------------------------------------
// 7) top-48: tau-prune + compact + sort (verified r3-r6)
// ---------------------------------------------------------------------------
__device__ __forceinline__ float sort64_desc(float v, int lane) {
    #pragma unroll
    for (int k = 2; k <= 64; k <<= 1) {
        #pragma unroll
        for (int j = k >> 1; j > 0; j >>= 1) {
            float o = __shfl_xor(v, j);
            bool takeMax = (((lane & k) == 0) == ((lane & j) == 0));
            v = takeMax ? fmaxf(v, o) : fminf(v, o);
        }
    }
    return v;
}
__device__ __forceinline__ float bmerge64_desc(float a, float b, int lane) {
    float br = __shfl(b, 63 - lane);
    float c = fmaxf(a, br);
    #pragma unroll
    for (int j = 32; j > 0; j >>= 1) {
        float o = __shfl_xor(c, j);
        c = ((lane & j) == 0) ? fmaxf(c, o) : fminf(c, o);
    }
    return c;
}

__global__ __launch_bounds__(256) void k_topk(const float* __restrict__ corr,
                                              float* __restrict__ topv) {
    int row = blockIdx.x, tid = threadIdx.x, wave = tid >> 6, lane = tid & 63;
    const float4 e = ((const float4*)(corr + (size_t)row * HW_))[tid];
    float gm = fmaxf(fmaxf(e.x, e.y), fmaxf(e.z, e.w));
    float v = sort64_desc(gm, lane);

    __shared__ float ls[4][64];
    __shared__ float tau_s;
    __shared__ int cnt_s;
    __shared__ float buf[1024];
    ls[wave][lane] = v;
    buf[tid] = -INFINITY; buf[tid + 256] = -INFINITY;
    buf[tid + 512] = -INFINITY; buf[tid + 768] = -INFINITY;
    if (tid == 0) cnt_s = 0;
    __syncthreads();

    if (wave == 0) {
        float ab = bmerge64_desc(ls[0][lane], ls[1][lane], lane);
        float cd = bmerge64_desc(ls[2][lane], ls[3][lane], lane);
        float t  = bmerge64_desc(ab, cd, lane);
        if (lane == T_ - 1) tau_s = t;
    }
    __syncthreads();
    float tau = tau_s;

    int c = (e.x >= tau) + (e.y >= tau) + (e.z >= tau) + (e.w >= tau);
    int off = 0;
    if (c) off = atomicAdd(&cnt_s, c);
    if (e.x >= tau) buf[off++] = e.x;
    if (e.y >= tau) buf[off++] = e.y;
    if (e.z >= tau) buf[off++] = e.z;
    if (e.w >= tau) buf[off++] = e.w;
    __syncthreads();
    int cnt = cnt_s;

    if (cnt <= 128) {
        if (wave == 0) {
            float a  = sort64_desc(buf[lane], lane);
            float b2 = sort64_desc(buf[64 + lane], lane);
            float br = __shfl(b2, 63 - lane);
            float hi = fmaxf(a, br);
            #pragma unroll
            for (int j = 32; j > 0; j >>= 1) {
                float o = __shfl_xor(hi, j);
                hi = ((lane & j) == 0) ? fmaxf(hi, o) : fminf(hi, o);
            }
            if (lane < T_) topv[(size_t)row * T_ + lane] = fmaxf(hi, 0.f);
        }
    } else {
        int P = 256; while (P < cnt) P <<= 1;
        for (int k = 2; k <= P; k <<= 1)
            for (int j = k >> 1; j > 0; j >>= 1) {
                for (int t2 = tid; t2 < P; t2 += 256) {
                    int ixj = t2 ^ j;
                    if (ixj > t2) {
                        float a = buf[t2], b3 = buf[ixj];
                        bool desc = ((t2 & k) == 0);
                        if (desc ? (a < b3) : (a > b3)) { buf[t2] = b3; buf[ixj] = a; }
                    }
                }
                __syncthreads();
            }
        if (tid < T_) topv[(size_t)row * T_ + tid] = fmaxf(buf[tid], 0.f);
    }
}

// ---------------------------------------------------------------------------
// 8) column norm over (B,H) and final transpose
// ---------------------------------------------------------------------------
__global__ void k_colss(const float* __restrict__ topv, float* __restrict__ colss) {
    int o = blockIdx.x;
    int w = o / T_, t = o % T_;
    int lane = threadIdx.x;
    float s = 0.f;
    for (int i = lane; i < 512; i += 64) {
        int b = i >> 5, h = i & 31;
        float v = topv[(size_t)((b << 10) + (h << 5) + w) * T_ + t];
        s += v * v;
    }
    for (int off = 32; off > 0; off >>= 1) s += __shfl_down(s, off);
    if (lane == 0) colss[o] = s;
}

__global__ void k_final(const float* __restrict__ topv, const float* __restrict__ colss,
                        float* __restrict__ out) {
    int idx = blockIdx.x * 256 + threadIdx.x;
    if (idx >= B_ * T_ * HW_) return;
    int w = idx & 31;
    int h = (idx >> 5) & 31;
    int t = (idx >> 10) % T_;
    int b = idx / (T_ * HW_);
    float v = topv[(size_t)((b << 10) + (h << 5) + w) * T_ + t];
    out[idx] = v * rsqrtf(colss[w * T_ + t]);
}

// ---------------------------------------------------------------------------
extern "C" void kernel_launch(void* const* d_in, const int* in_sizes, int n_in,
                              void* d_out, int out_size, void* d_ws, size_t ws_size,
                              hipStream_t stream) {
    const float* x     = (const float*)d_in[0];
    const float* fW    = (const float*)d_in[1];
    const float* fb    = (const float*)d_in[2];
    const float* gW    = (const float*)d_in[3];
    const float* gb    = (const float*)d_in[4];
    const float* hW    = (const float*)d_in[5];
    const float* hb    = (const float*)d_in[6];
    const float* scale = (const float*)d_in[7];
    float* out = (float*)d_out;

    // byte-offset workspace layout (unchanged; lo-plane regions now unused)
    char* wsb = (char*)d_ws;
    float* part = (float*)(wsb + 0);                 // 131072 B
    float* ninv = (float*)(wsb + 131072);            // 4096 B
    u16*   hWh  = (u16*)(wsb + 135168);              // 524288 B
    u16*   fgWh = (u16*)(wsb + 1183744);             // 131072 B
    float* fgb  = (float*)(wsb + 1445888);           // 512 B
    u16*   xnH  = (u16*)(wsb + 1446400);             // 16 MB (xn bf16 -> fdd bf16)
    u16*   fgH  = (u16*)(wsb + 35000832);            // 4 MB (f|g bf16; later topv)
    u16*   fgL  = (u16*)(wsb + 39195136);            // 4 MB (later colss)
    u16*   hvTH = (u16*)(wsb + 43389440);            // 16 MB (hv bf16 -> fddT)
    float* S    = (float*)(wsb + 76943872);          // 64 MB (S/P u16 -> corr fp32)
    float* topv = (float*)fgH;
    float* colss= (float*)fgL;
    u16*   Sp   = (u16*)S;

    const long sXn = 524288;    // [1024][512] elements per batch
    const long sFG = 131072;    // [1024][128]
    const long sS  = 1048576;   // [1024][1024]

    // 1) per-pixel Frobenius norm
    k_colsq<<<128, 256, 0, stream>>>(x, part);
    k_rsqrt<<<4, 256, 0, stream>>>(part, ninv);

    // 2) normalized channel-last bf16 (single plane)
    k_transpose<<<dim3(32, 16, 16), dim3(32, 8), 0, stream>>>(x, ninv, xnH);

    // 3) weight planes
    k_packW<<<1024, 256, 0, stream>>>(hW, hWh);
    k_packFG<<<256, 256, 0, stream>>>(fW, gW, fb, gb, fgWh, fgb);

    // 4) fg = bf16(xn @ [fW|gW]^T + bias[col])  [B,1024,128]
    k_gemm1<0, 6, 2><<<dim3(1, 8, 16), 256, 0, stream>>>(
        xnH, fgWh, fgb, nullptr, fgH, nullptr,
        128, 512, 512, 512, sXn, 0, sFG);

    // 5) hv = bf16(hW @ xn^T + hb[row])  [B,512,1024]
    k_gemm2<0, 5, 2><<<dim3(4, 4, 16), 512, 0, stream>>>(
        hWh, xnH, hb, nullptr, hvTH, nullptr,
        1024, 512, 512, 512, 0, sXn, sXn);

    // 6) S = bf16(f @ perm(g)^T)  (K=64, W-major keys)
    k_gemm2<1, 4, 2><<<dim3(4, 8, 16), 512, 0, stream>>>(
        fgH, fgH + 64, nullptr, nullptr, Sp, nullptr,
        1024, 64, 128, 128, sFG, sFG, sS);

    // 7) softmax rows, u16 in place -> P bf16
    k_softmax<<<B_ * HW_, 256, 0, stream>>>(Sp);

    // 8) fdd = bf16(scale*(P @ hv^T) + xn), in place over xnH
    k_gemm1<0, 2, 2><<<dim3(4, 8, 16), 256, 0, stream>>>(
        Sp, hvTH, nullptr, nullptr, xnH, scale,
        512, 1024, 1024, 1024, sS, sXn, sXn);

    // 9) fddT: transpose flat [512][1024] view of fddH -> hvTH [1024][512]
    k_tposeU1<<<dim3(32, 16, 16), dim3(32, 8), 0, stream>>>(xnH, hvTH);

    // 10) corr = fdd @ fddT^T -> fp32 into S
    k_gemm2<0, 0, 2><<<dim3(4, 8, 16), 512, 0, stream>>>(
        xnH, hvTH, nullptr, S, nullptr, nullptr,
        1024, 512, 512, 512, sXn, sXn, sS);

    // 11) top-48 desc + relu
    k_topk<<<B_ * HW_, 256, 0, stream>>>(S, topv);

    // 12) norm over (B,H) + output transpose
    k_colss<<<W_ * T_, 64, 0, stream>>>(topv, colss);
    k_final<<<(B_ * T_ * HW_ + 255) / 256, 256, 0, stream>>>(topv, colss, out);
}